// Round 17
// baseline (375.493 us; speedup 1.0000x reference)
//
#include <hip/hip_runtime.h>

typedef __attribute__((ext_vector_type(8))) short short8;
typedef __attribute__((ext_vector_type(16))) float f32x16;

union Frag { short8 v; unsigned u[4]; };

__device__ __forceinline__ unsigned pack_bf16(float lo, float hi) {
    unsigned r;
    asm volatile("v_cvt_pk_bf16_f32 %0, %1, %2" : "=v"(r) : "v"(lo), "v"(hi));
    return r;
}

#define BSHIFT 6
#define BROWS 64
#define MAXNB 2048
#define CHUNK 8192

// ---- k0: weight f32 -> bf16 (RNE) ----
__global__ __launch_bounds__(256)
void k_wconv(const float* __restrict__ w, unsigned short* __restrict__ wb, int n) {
    int i = (blockIdx.x * 256 + threadIdx.x) * 4;
    const int stride = gridDim.x * 1024;
    for (; i + 3 < n; i += stride) {
        const float4 v = *reinterpret_cast<const float4*>(w + i);
        ushort4 o;
        unsigned a;
        a = __float_as_uint(v.x); o.x = (unsigned short)((a + 0x7FFF + ((a >> 16) & 1)) >> 16);
        a = __float_as_uint(v.y); o.y = (unsigned short)((a + 0x7FFF + ((a >> 16) & 1)) >> 16);
        a = __float_as_uint(v.z); o.z = (unsigned short)((a + 0x7FFF + ((a >> 16) & 1)) >> 16);
        a = __float_as_uint(v.w); o.w = (unsigned short)((a + 0x7FFF + ((a >> 16) & 1)) >> 16);
        *reinterpret_cast<ushort4*>(wb + i) = o;
    }
}

// ---- k1: per-chunk LDS hist over 64-dst buckets ----
__global__ __launch_bounds__(256)
void k_hist(const int* __restrict__ dst, int* __restrict__ ghist, int E, int NB) {
    __shared__ int h[MAXNB];
    const int tid = threadIdx.x;
    for (int b = tid; b < NB; b += 256) h[b] = 0;
    __syncthreads();
    const int c0 = blockIdx.x * CHUNK;
    const int c1 = min(c0 + CHUNK, E);
    for (int i = c0 + tid; i < c1; i += 256) atomicAdd(&h[dst[i] >> BSHIFT], 1);
    __syncthreads();
    for (int b = tid; b < NB; b += 256) {
        const int cnt = h[b];
        if (cnt) atomicAdd(&ghist[b], cnt);
    }
}

// ---- k2: exclusive scan -> gcursor/gbase; also dstart[N_DST]=E ----
__global__ __launch_bounds__(512)
void k_scan(const int* __restrict__ ghist, int* __restrict__ gcursor,
            int* __restrict__ gbase, int* __restrict__ dstart, int NB, int E, int N_DST) {
    __shared__ int wsum[8];
    const int tid = threadIdx.x, lane = tid & 63, wv = tid >> 6;
    const int i0 = tid * 4;
    const int4 v = *reinterpret_cast<const int4*>(ghist + i0);
    const int s0 = v.x, s1 = s0 + v.y, s2 = s1 + v.z, s3 = s2 + v.w;
    int s = s3;
#pragma unroll
    for (int off = 1; off < 64; off <<= 1) {
        const int t = __shfl_up(s, off, 64);
        if (lane >= off) s += t;
    }
    if (lane == 63) wsum[wv] = s;
    __syncthreads();
    int wbase = 0;
    for (int w = 0; w < wv; ++w) wbase += wsum[w];
    const int tb = wbase + s - s3;
    if (i0 + 0 < NB) { gcursor[i0 + 0] = tb;      gbase[i0 + 0] = tb; }
    if (i0 + 1 < NB) { gcursor[i0 + 1] = tb + s0; gbase[i0 + 1] = tb + s0; }
    if (i0 + 2 < NB) { gcursor[i0 + 2] = tb + s1; gbase[i0 + 2] = tb + s1; }
    if (i0 + 3 < NB) { gcursor[i0 + 3] = tb + s2; gbase[i0 + 3] = tb + s2; }
    if (tid == 0) { gbase[NB] = E; dstart[N_DST] = E; }
}

// ---- k3: bucket scatter; fat recs {eid, src|dl<<20} ----
__global__ __launch_bounds__(256)
void k_scatter(const int* __restrict__ src, const int* __restrict__ dst,
               int* __restrict__ gcursor, int2* __restrict__ recs, int E, int NB) {
    __shared__ int cur[MAXNB];
    const int tid = threadIdx.x;
    for (int b = tid; b < NB; b += 256) cur[b] = 0;
    __syncthreads();
    const int c0 = blockIdx.x * CHUNK;
    const int c1 = min(c0 + CHUNK, E);
    for (int i = c0 + tid; i < c1; i += 256) atomicAdd(&cur[dst[i] >> BSHIFT], 1);
    __syncthreads();
    for (int b = tid; b < NB; b += 256) {
        const int cnt = cur[b];
        if (cnt) cur[b] = atomicAdd(&gcursor[b], cnt);
    }
    __syncthreads();
    for (int i = c0 + tid; i < c1; i += 256) {
        const int d = dst[i];
        const int slot = atomicAdd(&cur[d >> BSHIFT], 1);
        recs[slot] = make_int2(i, (src[i] & 0xFFFFF) | ((d & (BROWS - 1)) << 20));
    }
}

// ---- k3b: exact-dst sort within bucket -> pos[eid]=slot, dstart[d] ----
__global__ __launch_bounds__(256)
void k_sortb(const int2* __restrict__ recs, const int* __restrict__ gbase,
             int* __restrict__ pos, int* __restrict__ dstart, int N_DST) {
    __shared__ int bins[BROWS];
    const int tid = threadIdx.x;
    const int lane = tid & 63;
    const int b = blockIdx.x;
    const int start = gbase[b], end = gbase[b + 1];
    const int n = end - start;
    const int rowbase = b << BSHIFT;
    if (tid < BROWS) bins[tid] = 0;
    __syncthreads();
    for (int i = tid; i < n; i += 256)
        atomicAdd(&bins[(recs[start + i].y >> 20) & (BROWS - 1)], 1);
    __syncthreads();
    if (tid < BROWS) {
        const int v = bins[tid];
        int s = v;
#pragma unroll
        for (int off = 1; off < 64; off <<= 1) {
            const int t = __shfl_up(s, off, 64);
            if (lane >= off) s += t;
        }
        const int excl = s - v;
        if (rowbase + tid < N_DST) dstart[rowbase + tid] = start + excl;
        bins[tid] = excl;
    }
    __syncthreads();
    for (int i = tid; i < n; i += 256) {
        const int2 r = recs[start + i];
        const int dl = (r.y >> 20) & (BROWS - 1);
        const int slot = start + atomicAdd(&bins[dl], 1);
        pos[r.x] = slot;
    }
}

// ---- shared batch body (fallback path only; f32 weight, atomics) ----
__device__ __forceinline__ void batch_body(
    int eid, int se, int d, float cjci, const Frag bf[2][4],
    const float4* __restrict__ pw4, const float4* __restrict__ sw4,
    const float4* __restrict__ ft4,
    const float* __restrict__ weight, float* __restrict__ out,
    int h, int c, int& prev_d, float& r0acc, float& r1acc)
{
    Frag af[4];
    float px = 0.0f, sx = 0.0f;
#pragma unroll
    for (int s = 0; s < 4; ++s) {
        const size_t base = (size_t)eid * 16 + 4 * s + 2 * h;
        const float4 f0 = ft4[base];
        const float4 f1 = ft4[base + 1];
        const float4 p0 = pw4[4 * s + 2 * h];
        const float4 p1 = pw4[4 * s + 2 * h + 1];
        const float4 q0 = sw4[4 * s + 2 * h];
        const float4 q1 = sw4[4 * s + 2 * h + 1];
        px += f0.x * p0.x + f0.y * p0.y + f0.z * p0.z + f0.w * p0.w
            + f1.x * p1.x + f1.y * p1.y + f1.z * p1.z + f1.w * p1.w;
        sx += f0.x * q0.x + f0.y * q0.y + f0.z * q0.z + f0.w * q0.w
            + f1.x * q1.x + f1.y * q1.y + f1.z * q1.z + f1.w * q1.w;
        af[s].u[0] = pack_bf16(f0.x, f0.y);
        af[s].u[1] = pack_bf16(f0.z, f0.w);
        af[s].u[2] = pack_bf16(f1.x, f1.y);
        af[s].u[3] = pack_bf16(f1.z, f1.w);
    }
    px += __shfl_xor(px, 32, 64);
    sx += __shfl_xor(sx, 32, 64);
    const float pa = __fdividef(1.0f, 1.0f + __expf(-px));
    const float gs = __fdividef(1.0f, 1.0f + __expf(-sx));
    const float Ae = pa * cjci;
    const float Be = gs * cjci;

    f32x16 acc0 = {0.0f};
    f32x16 acc1 = {0.0f};
#pragma unroll
    for (int s = 0; s < 4; ++s) {
        acc0 = __builtin_amdgcn_mfma_f32_32x32x16_bf16(af[s].v, bf[0][s].v, acc0, 0, 0, 0);
        acc1 = __builtin_amdgcn_mfma_f32_32x32x16_bf16(af[s].v, bf[1][s].v, acc1, 0, 0, 0);
    }
#pragma unroll
    for (int r = 0; r < 16; ++r) {
        const int e_lr = (r & 3) + 8 * (r >> 2) + 4 * h;
        const float Ar = __shfl(Ae, e_lr, 64);
        const float Br = __shfl(Be, e_lr, 64);
        const int sr = __shfl(se, e_lr, 64);
        const int dr = __shfl(d, e_lr, 64);
        const float w0 = weight[sr * 64 + c];
        const float w1 = weight[sr * 64 + 32 + c];
        const float m0 = acc0[r] * Br + w0 * Ar;
        const float m1 = acc1[r] * Br + w1 * Ar;
        if (__any(dr != prev_d)) {
            if (dr != prev_d) {
                if (prev_d >= 0) {
                    unsafeAtomicAdd(&out[(size_t)prev_d * 64 + c], r0acc);
                    unsafeAtomicAdd(&out[(size_t)prev_d * 64 + 32 + c], r1acc);
                }
                r0acc = 0.0f; r1acc = 0.0f; prev_d = dr;
            }
        }
        r0acc += m0;
        r1acc += m1;
    }
}

// ---- P1: edge-order streaming compute; scatter bf16 messages to sorted slots ----
__global__ __launch_bounds__(256, 2)
void k_p1(const unsigned short* __restrict__ weightB, const float* __restrict__ prob_w,
          const float* __restrict__ rscore_w, const float* __restrict__ review_w,
          const float* __restrict__ feat, const float* __restrict__ cj,
          const int* __restrict__ src_idx, const int* __restrict__ pos,
          unsigned* __restrict__ msg, int E)
{
    const int lane = threadIdx.x & 63;
    const int h = lane >> 5;
    const int c = lane & 31;
    const int wid = blockIdx.x * (blockDim.x >> 6) + (threadIdx.x >> 6);
    const int nw = gridDim.x * (blockDim.x >> 6);

    const float4* rw4 = reinterpret_cast<const float4*>(review_w);
    const float4* pw4 = reinterpret_cast<const float4*>(prob_w);
    const float4* sw4 = reinterpret_cast<const float4*>(rscore_w);
    const float4* ft4 = reinterpret_cast<const float4*>(feat);

    Frag bf[2][4];
#pragma unroll
    for (int t = 0; t < 2; ++t) {
#pragma unroll
        for (int s = 0; s < 4; ++s) {
            const float4 r0 = rw4[(32 * t + c) * 16 + 4 * s + 2 * h];
            const float4 r1 = rw4[(32 * t + c) * 16 + 4 * s + 2 * h + 1];
            bf[t][s].u[0] = pack_bf16(r0.x, r0.y);
            bf[t][s].u[1] = pack_bf16(r0.z, r0.w);
            bf[t][s].u[2] = pack_bf16(r1.x, r1.y);
            bf[t][s].u[3] = pack_bf16(r1.z, r1.w);
        }
    }

    const int nbt = (E + 31) >> 5;
    for (int bt = wid; bt < nbt; bt += nw) {
        const int e = (bt << 5) + c;
        const bool valid = e < E;
        const int ec = min(e, E - 1);
        const int se = src_idx[ec];
        const int slot = valid ? pos[ec] : E;     // invalid -> dummy row E
        const float cjv = valid ? cj[se] : 0.0f;

        // burst: packed bf16 weight loads (hoisted, independent)
        unsigned wp[16];
#pragma unroll
        for (int r = 0; r < 16; ++r) {
            const int e_lr = (r & 3) + 8 * (r >> 2) + 4 * h;
            const int sr = __shfl(se, e_lr, 64);
            const unsigned u0 = weightB[sr * 64 + c];
            const unsigned u1 = weightB[sr * 64 + 32 + c];
            wp[r] = u0 | (u1 << 16);
        }

        // feat (sequential region) + gates + A fragments
        Frag af[4];
        float px = 0.0f, sx = 0.0f;
#pragma unroll
        for (int s = 0; s < 4; ++s) {
            const size_t base = (size_t)ec * 16 + 4 * s + 2 * h;
            const float4 f0 = ft4[base];
            const float4 f1 = ft4[base + 1];
            const float4 p0 = pw4[4 * s + 2 * h];
            const float4 p1 = pw4[4 * s + 2 * h + 1];
            const float4 q0 = sw4[4 * s + 2 * h];
            const float4 q1 = sw4[4 * s + 2 * h + 1];
            px += f0.x * p0.x + f0.y * p0.y + f0.z * p0.z + f0.w * p0.w
                + f1.x * p1.x + f1.y * p1.y + f1.z * p1.z + f1.w * p1.w;
            sx += f0.x * q0.x + f0.y * q0.y + f0.z * q0.z + f0.w * q0.w
                + f1.x * q1.x + f1.y * q1.y + f1.z * q1.z + f1.w * q1.w;
            af[s].u[0] = pack_bf16(f0.x, f0.y);
            af[s].u[1] = pack_bf16(f0.z, f0.w);
            af[s].u[2] = pack_bf16(f1.x, f1.y);
            af[s].u[3] = pack_bf16(f1.z, f1.w);
        }
        px += __shfl_xor(px, 32, 64);
        sx += __shfl_xor(sx, 32, 64);
        const float pa = __fdividef(1.0f, 1.0f + __expf(-px));
        const float gs = __fdividef(1.0f, 1.0f + __expf(-sx));
        const float Ae = pa * cjv;
        const float Be = gs * cjv;

        f32x16 acc0 = {0.0f};
        f32x16 acc1 = {0.0f};
#pragma unroll
        for (int s = 0; s < 4; ++s) {
            acc0 = __builtin_amdgcn_mfma_f32_32x32x16_bf16(af[s].v, bf[0][s].v, acc0, 0, 0, 0);
            acc1 = __builtin_amdgcn_mfma_f32_32x32x16_bf16(af[s].v, bf[1][s].v, acc1, 0, 0, 0);
        }

        // scatter bf16 message rows: per r, each half stores 128B coalesced
#pragma unroll
        for (int r = 0; r < 16; ++r) {
            const int e_lr = (r & 3) + 8 * (r >> 2) + 4 * h;
            const float Ar = __shfl(Ae, e_lr, 64);
            const float Br = __shfl(Be, e_lr, 64);
            const int sl = __shfl(slot, e_lr, 64);
            const float w0 = __uint_as_float((wp[r] & 0xFFFFu) << 16);
            const float w1 = __uint_as_float(wp[r] & 0xFFFF0000u);
            const float m0 = acc0[r] * Br + w0 * Ar;
            const float m1 = acc1[r] * Br + w1 * Ar;
            msg[(size_t)sl * 32 + c] = pack_bf16(m0, m1);
        }
    }
}

// ---- P2: streaming per-dst reduce; no atomics; writes out directly ----
__global__ __launch_bounds__(256)
void k_p2(const unsigned* __restrict__ msg, const int* __restrict__ dstart,
          const float* __restrict__ ci, float* __restrict__ out, int N_DST)
{
    const int g = threadIdx.x >> 5;
    const int c = threadIdx.x & 31;
    const int d = blockIdx.x * 8 + g;
    if (d >= N_DST) return;
    const int s0 = dstart[d], s1 = dstart[d + 1];
    float a0 = 0.0f, a1 = 0.0f;
    for (int s = s0; s < s1; ++s) {
        const unsigned u = msg[(size_t)s * 32 + c];
        a0 += __uint_as_float((u & 0xFFFFu) << 16);
        a1 += __uint_as_float(u & 0xFFFF0000u);
    }
    const float civ = ci[d];
    out[(size_t)d * 64 + c] = a0 * civ;
    out[(size_t)d * 64 + 32 + c] = a1 * civ;
}

// ---- fallback: direct kernel (ws too small / sizes out of range) ----
__global__ __launch_bounds__(256, 2)
void k_direct(const float* __restrict__ weight, const float* __restrict__ prob_w,
              const float* __restrict__ rscore_w, const float* __restrict__ review_w,
              const float* __restrict__ feat, const float* __restrict__ cj,
              const float* __restrict__ ci, const int* __restrict__ src_idx,
              const int* __restrict__ dst_idx, float* __restrict__ out, int E)
{
    const int lane = threadIdx.x & 63;
    const int h = lane >> 5, c = lane & 31;
    const int wid = blockIdx.x * (blockDim.x >> 6) + (threadIdx.x >> 6);
    const int nw = gridDim.x * (blockDim.x >> 6);
    const float4* rw4 = reinterpret_cast<const float4*>(review_w);
    const float4* pw4 = reinterpret_cast<const float4*>(prob_w);
    const float4* sw4 = reinterpret_cast<const float4*>(rscore_w);
    const float4* ft4 = reinterpret_cast<const float4*>(feat);
    Frag bf[2][4];
#pragma unroll
    for (int t = 0; t < 2; ++t)
#pragma unroll
        for (int s = 0; s < 4; ++s) {
            const float4 r0 = rw4[(32 * t + c) * 16 + 4 * s + 2 * h];
            const float4 r1 = rw4[(32 * t + c) * 16 + 4 * s + 2 * h + 1];
            bf[t][s].u[0] = pack_bf16(r0.x, r0.y);
            bf[t][s].u[1] = pack_bf16(r0.z, r0.w);
            bf[t][s].u[2] = pack_bf16(r1.x, r1.y);
            bf[t][s].u[3] = pack_bf16(r1.z, r1.w);
        }
    const int ntot = (E + 31) >> 5;
    for (int bt = wid; bt < ntot; bt += nw) {
        const int idx = (bt << 5) + c;
        const bool valid = idx < E;
        const int eid = valid ? idx : 0;
        const int se = src_idx[eid];
        const int d = dst_idx[eid];
        const float cjci = valid ? cj[se] * ci[d] : 0.0f;
        int pd = -1;
        float a0 = 0.0f, a1 = 0.0f;
        batch_body(eid, se, d, cjci, bf, pw4, sw4, ft4, weight, out,
                   h, c, pd, a0, a1);
        if (pd >= 0) {
            unsafeAtomicAdd(&out[(size_t)pd * 64 + c], a0);
            unsafeAtomicAdd(&out[(size_t)pd * 64 + 32 + c], a1);
        }
    }
}

extern "C" void kernel_launch(void* const* d_in, const int* in_sizes, int n_in,
                              void* d_out, int out_size, void* d_ws, size_t ws_size,
                              hipStream_t stream) {
    const float* weight    = (const float*)d_in[0];
    const float* prob_w    = (const float*)d_in[1];
    const float* rscore_w  = (const float*)d_in[2];
    const float* review_w  = (const float*)d_in[3];
    const float* feat      = (const float*)d_in[4];
    const float* cj        = (const float*)d_in[5];
    const float* ci        = (const float*)d_in[6];
    const int*   src_idx   = (const int*)d_in[7];
    const int*   dst_idx   = (const int*)d_in[8];
    float* out = (float*)d_out;
    const int E = in_sizes[7];
    const int N_DST = in_sizes[6];
    const int N_SRC = in_sizes[0] / 64;
    const int NB = (N_DST + BROWS - 1) >> BSHIFT;   // 1563 for N_DST=100000

    // ws layout (aligned chunks):
    // [0)      ghist[2048] | gcursor[2048] | gbase[2049]        (32 KB)
    // recs     int2[E]
    // pos      int[E]
    // dstart   int[N_DST+1]
    // weightB  ushort[N_SRC*64]
    // msg      u32[(E+1)*32]
    const size_t rec_off = 32768;
    const size_t pos_off = rec_off + ((size_t)E * sizeof(int2) + 255 & ~(size_t)255);
    const size_t dst_off = pos_off + ((size_t)E * sizeof(int) + 255 & ~(size_t)255);
    const size_t wb_off  = dst_off + (((size_t)N_DST + 1) * sizeof(int) + 255 & ~(size_t)255);
    const size_t msg_off = wb_off + ((size_t)N_SRC * 64 * sizeof(unsigned short) + 255 & ~(size_t)255);
    const size_t need    = msg_off + (size_t)(E + 1) * 32 * sizeof(unsigned);
    if (ws_size < need || NB > MAXNB - 1 || N_SRC > (1 << 20)) {
        hipMemsetAsync(d_out, 0, (size_t)out_size * sizeof(float), stream);
        k_direct<<<2048, 256, 0, stream>>>(weight, prob_w, rscore_w, review_w, feat,
                                           cj, ci, src_idx, dst_idx, out, E);
        return;
    }
    int* ghist   = (int*)d_ws;
    int* gcursor = ghist + 2048;
    int* gbase   = ghist + 4096;
    int2* recs   = (int2*)((char*)d_ws + rec_off);
    int* pos     = (int*)((char*)d_ws + pos_off);
    int* dstart  = (int*)((char*)d_ws + dst_off);
    unsigned short* weightB = (unsigned short*)((char*)d_ws + wb_off);
    unsigned* msg = (unsigned*)((char*)d_ws + msg_off);

    hipMemsetAsync(ghist, 0, 2048 * sizeof(int), stream);

    const int nchunk = (E + CHUNK - 1) / CHUNK;
    k_wconv<<<1024, 256, 0, stream>>>(weight, weightB, N_SRC * 64);
    k_hist<<<nchunk, 256, 0, stream>>>(dst_idx, ghist, E, NB);
    k_scan<<<1, 512, 0, stream>>>(ghist, gcursor, gbase, dstart, NB, E, N_DST);
    k_scatter<<<nchunk, 256, 0, stream>>>(src_idx, dst_idx, gcursor, recs, E, NB);
    k_sortb<<<NB, 256, 0, stream>>>(recs, gbase, pos, dstart, N_DST);
    k_p1<<<2048, 256, 0, stream>>>(weightB, prob_w, rscore_w, review_w, feat,
                                   cj, src_idx, pos, msg, E);
    k_p2<<<(N_DST + 7) / 8, 256, 0, stream>>>(msg, dstart, ci, out, N_DST);
}

// Round 18
// 254.035 us; speedup vs baseline: 1.4781x; 1.4781x over previous
//
#include <hip/hip_runtime.h>

typedef __attribute__((ext_vector_type(8))) short short8;
typedef __attribute__((ext_vector_type(16))) float f32x16;

union Frag { short8 v; unsigned u[4]; };

__device__ __forceinline__ unsigned pack_bf16(float lo, float hi) {
    unsigned r;
    asm volatile("v_cvt_pk_bf16_f32 %0, %1, %2" : "=v"(r) : "v"(lo), "v"(hi));
    return r;
}

#define BSHIFT 6
#define BROWS 64             // dst rows per bucket
#define MAXNB 2048
#define CHUNK 8192           // edges per hist/scatter block

// ---- k0: weight f32 -> bf16 (RNE) ----
__global__ __launch_bounds__(256)
void k_wconv(const float* __restrict__ w, unsigned short* __restrict__ wb, int n) {
    int i = (blockIdx.x * 256 + threadIdx.x) * 4;
    const int stride = gridDim.x * 1024;
    for (; i + 3 < n; i += stride) {
        const float4 v = *reinterpret_cast<const float4*>(w + i);
        ushort4 o;
        unsigned a;
        a = __float_as_uint(v.x); o.x = (unsigned short)((a + 0x7FFF + ((a >> 16) & 1)) >> 16);
        a = __float_as_uint(v.y); o.y = (unsigned short)((a + 0x7FFF + ((a >> 16) & 1)) >> 16);
        a = __float_as_uint(v.z); o.z = (unsigned short)((a + 0x7FFF + ((a >> 16) & 1)) >> 16);
        a = __float_as_uint(v.w); o.w = (unsigned short)((a + 0x7FFF + ((a >> 16) & 1)) >> 16);
        *reinterpret_cast<ushort4*>(wb + i) = o;
    }
}

// ---- k1: per-chunk LDS hist, one global atomic per (block,bucket) ----
__global__ __launch_bounds__(256)
void k_hist(const int* __restrict__ dst, int* __restrict__ ghist, int E, int NB) {
    __shared__ int h[MAXNB];
    const int tid = threadIdx.x;
    for (int b = tid; b < NB; b += 256) h[b] = 0;
    __syncthreads();
    const int c0 = blockIdx.x * CHUNK;
    const int c1 = min(c0 + CHUNK, E);
    for (int i = c0 + tid; i < c1; i += 256) atomicAdd(&h[dst[i] >> BSHIFT], 1);
    __syncthreads();
    for (int b = tid; b < NB; b += 256) {
        const int cnt = h[b];
        if (cnt) atomicAdd(&ghist[b], cnt);
    }
}

// ---- k2: exclusive scan of NB (<=2048) bins -> gcursor, gbase; gbase[NB]=E ----
__global__ __launch_bounds__(512)
void k_scan(const int* __restrict__ ghist, int* __restrict__ gcursor,
            int* __restrict__ gbase, int NB, int E) {
    __shared__ int wsum[8];
    const int tid = threadIdx.x, lane = tid & 63, wv = tid >> 6;
    const int i0 = tid * 4;                     // covers 2048 (ghist zero-padded)
    const int4 v = *reinterpret_cast<const int4*>(ghist + i0);
    const int s0 = v.x, s1 = s0 + v.y, s2 = s1 + v.z, s3 = s2 + v.w;
    int s = s3;
#pragma unroll
    for (int off = 1; off < 64; off <<= 1) {
        const int t = __shfl_up(s, off, 64);
        if (lane >= off) s += t;
    }
    if (lane == 63) wsum[wv] = s;
    __syncthreads();
    int wbase = 0;
    for (int w = 0; w < wv; ++w) wbase += wsum[w];
    const int tb = wbase + s - s3;
    if (i0 + 0 < NB) { gcursor[i0 + 0] = tb;      gbase[i0 + 0] = tb; }
    if (i0 + 1 < NB) { gcursor[i0 + 1] = tb + s0; gbase[i0 + 1] = tb + s0; }
    if (i0 + 2 < NB) { gcursor[i0 + 2] = tb + s1; gbase[i0 + 2] = tb + s1; }
    if (i0 + 3 < NB) { gcursor[i0 + 3] = tb + s2; gbase[i0 + 3] = tb + s2; }
    if (tid == 0) gbase[NB] = E;
}

// ---- k3: claim once per (block,bucket); slot via LDS rtn-atomics; fat recs ----
__global__ __launch_bounds__(256)
void k_scatter(const int* __restrict__ src, const int* __restrict__ dst,
               int* __restrict__ gcursor, int2* __restrict__ recs, int E, int NB) {
    __shared__ int cur[MAXNB];
    const int tid = threadIdx.x;
    for (int b = tid; b < NB; b += 256) cur[b] = 0;
    __syncthreads();
    const int c0 = blockIdx.x * CHUNK;
    const int c1 = min(c0 + CHUNK, E);
    for (int i = c0 + tid; i < c1; i += 256) atomicAdd(&cur[dst[i] >> BSHIFT], 1);
    __syncthreads();
    for (int b = tid; b < NB; b += 256) {
        const int cnt = cur[b];
        if (cnt) cur[b] = atomicAdd(&gcursor[b], cnt);
    }
    __syncthreads();
    for (int i = c0 + tid; i < c1; i += 256) {
        const int d = dst[i];
        const int slot = atomicAdd(&cur[d >> BSHIFT], 1);
        recs[slot] = make_int2(i, (src[i] & 0xFFFFF) | ((d & (BROWS - 1)) << 20));
    }
}

// ---- k3b: exact-dst counting sort within each bucket; pack full info ----
// out rec: {eid | dl<<21, se | bucket<<20}
__global__ __launch_bounds__(256)
void k_sortbucket(const int2* __restrict__ recs, const int* __restrict__ gbase,
                  int2* __restrict__ recsS) {
    __shared__ int bins[BROWS];
    const int tid = threadIdx.x;
    const int lane = tid & 63;
    const int b = blockIdx.x;
    const int start = gbase[b], end = gbase[b + 1];
    const int n = end - start;
    if (tid < BROWS) bins[tid] = 0;
    __syncthreads();
    for (int i = tid; i < n; i += 256)
        atomicAdd(&bins[(recs[start + i].y >> 20) & (BROWS - 1)], 1);
    __syncthreads();
    if (tid < BROWS) {
        const int v = bins[tid];
        int s = v;
#pragma unroll
        for (int off = 1; off < 64; off <<= 1) {
            const int t = __shfl_up(s, off, 64);
            if (lane >= off) s += t;
        }
        bins[tid] = s - v;
    }
    __syncthreads();
    for (int i = tid; i < n; i += 256) {
        const int2 r = recs[start + i];
        const int dl = (r.y >> 20) & (BROWS - 1);
        const int slot = start + atomicAdd(&bins[dl], 1);
        recsS[slot] = make_int2(r.x | (dl << 21), (r.y & 0xFFFFF) | (b << 20));
    }
}

// ---- shared batch body (used by fallback path only; f32 weight) ----
__device__ __forceinline__ void batch_body(
    int eid, int se, int d, float cjci, const Frag bf[2][4],
    const float4* __restrict__ pw4, const float4* __restrict__ sw4,
    const float4* __restrict__ ft4,
    const float* __restrict__ weight, float* __restrict__ out,
    int h, int c, int& prev_d, float& r0acc, float& r1acc)
{
    Frag af[4];
    float px = 0.0f, sx = 0.0f;
#pragma unroll
    for (int s = 0; s < 4; ++s) {
        const size_t base = (size_t)eid * 16 + 4 * s + 2 * h;
        const float4 f0 = ft4[base];
        const float4 f1 = ft4[base + 1];
        const float4 p0 = pw4[4 * s + 2 * h];
        const float4 p1 = pw4[4 * s + 2 * h + 1];
        const float4 q0 = sw4[4 * s + 2 * h];
        const float4 q1 = sw4[4 * s + 2 * h + 1];
        px += f0.x * p0.x + f0.y * p0.y + f0.z * p0.z + f0.w * p0.w
            + f1.x * p1.x + f1.y * p1.y + f1.z * p1.z + f1.w * p1.w;
        sx += f0.x * q0.x + f0.y * q0.y + f0.z * q0.z + f0.w * q0.w
            + f1.x * q1.x + f1.y * q1.y + f1.z * q1.z + f1.w * q1.w;
        af[s].u[0] = pack_bf16(f0.x, f0.y);
        af[s].u[1] = pack_bf16(f0.z, f0.w);
        af[s].u[2] = pack_bf16(f1.x, f1.y);
        af[s].u[3] = pack_bf16(f1.z, f1.w);
    }
    px += __shfl_xor(px, 32, 64);
    sx += __shfl_xor(sx, 32, 64);
    const float pa = __fdividef(1.0f, 1.0f + __expf(-px));
    const float gs = __fdividef(1.0f, 1.0f + __expf(-sx));
    const float Ae = pa * cjci;
    const float Be = gs * cjci;

    f32x16 acc0 = {0.0f};
    f32x16 acc1 = {0.0f};
#pragma unroll
    for (int s = 0; s < 4; ++s) {
        acc0 = __builtin_amdgcn_mfma_f32_32x32x16_bf16(af[s].v, bf[0][s].v, acc0, 0, 0, 0);
        acc1 = __builtin_amdgcn_mfma_f32_32x32x16_bf16(af[s].v, bf[1][s].v, acc1, 0, 0, 0);
    }
#pragma unroll
    for (int r = 0; r < 16; ++r) {
        const int e_lr = (r & 3) + 8 * (r >> 2) + 4 * h;
        const float Ar = __shfl(Ae, e_lr, 64);
        const float Br = __shfl(Be, e_lr, 64);
        const int sr = __shfl(se, e_lr, 64);
        const int dr = __shfl(d, e_lr, 64);
        const float w0 = weight[sr * 64 + c];
        const float w1 = weight[sr * 64 + 32 + c];
        const float m0 = acc0[r] * Br + w0 * Ar;
        const float m1 = acc1[r] * Br + w1 * Ar;
        if (__any(dr != prev_d)) {
            if (dr != prev_d) {
                if (prev_d >= 0) {
                    unsafeAtomicAdd(&out[(size_t)prev_d * 64 + c], r0acc);
                    unsafeAtomicAdd(&out[(size_t)prev_d * 64 + 32 + c], r1acc);
                }
                r0acc = 0.0f; r1acc = 0.0f; prev_d = dr;
            }
        }
        r0acc += m0;
        r1acc += m1;
    }
}

// ---- k4: flat grid; COALESCED feat gather via per-wave LDS staging ----
// 4 adjacent lanes fetch 4 contiguous 16B chunks of ONE edge -> 64B requests
// (128 req/batch instead of 512). Stage in per-wave LDS, read in MFMA layout.
#define FROW 68   // floats per LDS feat row (64 data + 4 pad)
__global__ __launch_bounds__(256, 2)
void k_main(const unsigned short* __restrict__ weightB, const float* __restrict__ prob_w,
            const float* __restrict__ rscore_w, const float* __restrict__ review_w,
            const float* __restrict__ feat, const float* __restrict__ cj,
            const float* __restrict__ ci,
            const int2* __restrict__ recsS, float* __restrict__ out, int E)
{
    __shared__ float lds_feat[4][32 * FROW];   // 34816 B

    const int lane = threadIdx.x & 63;
    const int h = lane >> 5;
    const int c = lane & 31;
    const int w = threadIdx.x >> 6;
    const int wid = blockIdx.x * (blockDim.x >> 6) + w;
    const int nw = gridDim.x * (blockDim.x >> 6);

    const float4* rw4 = reinterpret_cast<const float4*>(review_w);
    const float4* pw4 = reinterpret_cast<const float4*>(prob_w);
    const float4* sw4 = reinterpret_cast<const float4*>(rscore_w);
    const float4* ft4 = reinterpret_cast<const float4*>(feat);
    float* myf = lds_feat[w];

    Frag bf[2][4];
#pragma unroll
    for (int t = 0; t < 2; ++t) {
#pragma unroll
        for (int s = 0; s < 4; ++s) {
            const float4 r0 = rw4[(32 * t + c) * 16 + 4 * s + 2 * h];
            const float4 r1 = rw4[(32 * t + c) * 16 + 4 * s + 2 * h + 1];
            bf[t][s].u[0] = pack_bf16(r0.x, r0.y);
            bf[t][s].u[1] = pack_bf16(r0.z, r0.w);
            bf[t][s].u[2] = pack_bf16(r1.x, r1.y);
            bf[t][s].u[3] = pack_bf16(r1.z, r1.w);
        }
    }

    // contiguous span of batches per wave -> run-length carry stays valid
    const int nbt = (E + 31) >> 5;
    const int q = nbt / nw, rr = nbt % nw;
    const int bt0 = wid * q + min(wid, rr);
    const int bt1 = bt0 + q + (wid < rr ? 1 : 0);

    int prev_d = -1;
    float r0acc = 0.0f, r1acc = 0.0f;
    for (int bt = bt0; bt < bt1; ++bt) {
        const int idx = (bt << 5) + c;
        const bool valid = idx < E;
        const int2 rec = recsS[min(idx, E - 1)];
        const int eid = rec.x & 0x1FFFFF;
        const int dl = (rec.x >> 21) & (BROWS - 1);
        const int se = rec.y & 0xFFFFF;
        const int bkt = (int)(((unsigned)rec.y) >> 20);
        const int d = (bkt << BSHIFT) | dl;
        const float cjci = valid ? cj[se] * ci[d] : 0.0f;

        // ---- burst 1: packed bf16 weight loads (shfl addressing) ----
        unsigned wp[16];
#pragma unroll
        for (int r = 0; r < 16; ++r) {
            const int e_lr = (r & 3) + 8 * (r >> 2) + 4 * h;
            const int sr = __shfl(se, e_lr, 64);
            const unsigned u0 = weightB[sr * 64 + c];
            const unsigned u1 = weightB[sr * 64 + 32 + c];
            wp[r] = u0 | (u1 << 16);
        }

        // ---- burst 2: coalesced feat gather -> per-wave LDS ----
        // instr k: 16 edges x 64B contiguous; lanes 4j..4j+3 share edge j's 64B
#pragma unroll
        for (int k = 0; k < 8; ++k) {
            const int e_loc = (lane >> 2) + 16 * (k & 1);
            const int chunk = (lane & 3) + 4 * (k >> 1);
            const int eid_e = __shfl(eid, e_loc, 64);     // lane e_loc holds edge e_loc
            const float4 v = ft4[(size_t)eid_e * 16 + chunk];
            *reinterpret_cast<float4*>(&myf[e_loc * FROW + chunk * 4]) = v;
        }

        // ---- gates + A fragments from LDS (MFMA layout) ----
        Frag af[4];
        float px = 0.0f, sx = 0.0f;
#pragma unroll
        for (int s = 0; s < 4; ++s) {
            const float4 f0 = *reinterpret_cast<const float4*>(&myf[c * FROW + (4 * s + 2 * h) * 4]);
            const float4 f1 = *reinterpret_cast<const float4*>(&myf[c * FROW + (4 * s + 2 * h) * 4 + 4]);
            const float4 p0 = pw4[4 * s + 2 * h];
            const float4 p1 = pw4[4 * s + 2 * h + 1];
            const float4 q0 = sw4[4 * s + 2 * h];
            const float4 q1 = sw4[4 * s + 2 * h + 1];
            px += f0.x * p0.x + f0.y * p0.y + f0.z * p0.z + f0.w * p0.w
                + f1.x * p1.x + f1.y * p1.y + f1.z * p1.z + f1.w * p1.w;
            sx += f0.x * q0.x + f0.y * q0.y + f0.z * q0.z + f0.w * q0.w
                + f1.x * q1.x + f1.y * q1.y + f1.z * q1.z + f1.w * q1.w;
            af[s].u[0] = pack_bf16(f0.x, f0.y);
            af[s].u[1] = pack_bf16(f0.z, f0.w);
            af[s].u[2] = pack_bf16(f1.x, f1.y);
            af[s].u[3] = pack_bf16(f1.z, f1.w);
        }
        px += __shfl_xor(px, 32, 64);
        sx += __shfl_xor(sx, 32, 64);
        const float pa = __fdividef(1.0f, 1.0f + __expf(-px));
        const float gs = __fdividef(1.0f, 1.0f + __expf(-sx));
        const float Ae = pa * cjci;
        const float Be = gs * cjci;

        f32x16 acc0 = {0.0f};
        f32x16 acc1 = {0.0f};
#pragma unroll
        for (int s = 0; s < 4; ++s) {
            acc0 = __builtin_amdgcn_mfma_f32_32x32x16_bf16(af[s].v, bf[0][s].v, acc0, 0, 0, 0);
            acc1 = __builtin_amdgcn_mfma_f32_32x32x16_bf16(af[s].v, bf[1][s].v, acc1, 0, 0, 0);
        }

        // ---- epilogue: pure VALU (weights pre-loaded), carry + atomics ----
#pragma unroll
        for (int r = 0; r < 16; ++r) {
            const int e_lr = (r & 3) + 8 * (r >> 2) + 4 * h;
            const float Ar = __shfl(Ae, e_lr, 64);
            const float Br = __shfl(Be, e_lr, 64);
            const int dr = __shfl(d, e_lr, 64);
            const float w0 = __uint_as_float((wp[r] & 0xFFFFu) << 16);
            const float w1 = __uint_as_float(wp[r] & 0xFFFF0000u);
            const float m0 = acc0[r] * Br + w0 * Ar;
            const float m1 = acc1[r] * Br + w1 * Ar;
            if (__any(dr != prev_d)) {
                if (dr != prev_d) {
                    if (prev_d >= 0) {
                        unsafeAtomicAdd(&out[(size_t)prev_d * 64 + c], r0acc);
                        unsafeAtomicAdd(&out[(size_t)prev_d * 64 + 32 + c], r1acc);
                    }
                    r0acc = 0.0f; r1acc = 0.0f; prev_d = dr;
                }
            }
            r0acc += m0;
            r1acc += m1;
        }
    }
    if (prev_d >= 0) {
        unsafeAtomicAdd(&out[(size_t)prev_d * 64 + c], r0acc);
        unsafeAtomicAdd(&out[(size_t)prev_d * 64 + 32 + c], r1acc);
    }
}

// ---- fallback (ws too small / sizes out of range): direct kernel ----
__global__ __launch_bounds__(256, 2)
void k_direct(const float* __restrict__ weight, const float* __restrict__ prob_w,
              const float* __restrict__ rscore_w, const float* __restrict__ review_w,
              const float* __restrict__ feat, const float* __restrict__ cj,
              const float* __restrict__ ci, const int* __restrict__ src_idx,
              const int* __restrict__ dst_idx, float* __restrict__ out, int E)
{
    const int lane = threadIdx.x & 63;
    const int h = lane >> 5, c = lane & 31;
    const int wid = blockIdx.x * (blockDim.x >> 6) + (threadIdx.x >> 6);
    const int nw = gridDim.x * (blockDim.x >> 6);
    const float4* rw4 = reinterpret_cast<const float4*>(review_w);
    const float4* pw4 = reinterpret_cast<const float4*>(prob_w);
    const float4* sw4 = reinterpret_cast<const float4*>(rscore_w);
    const float4* ft4 = reinterpret_cast<const float4*>(feat);
    Frag bf[2][4];
#pragma unroll
    for (int t = 0; t < 2; ++t)
#pragma unroll
        for (int s = 0; s < 4; ++s) {
            const float4 r0 = rw4[(32 * t + c) * 16 + 4 * s + 2 * h];
            const float4 r1 = rw4[(32 * t + c) * 16 + 4 * s + 2 * h + 1];
            bf[t][s].u[0] = pack_bf16(r0.x, r0.y);
            bf[t][s].u[1] = pack_bf16(r0.z, r0.w);
            bf[t][s].u[2] = pack_bf16(r1.x, r1.y);
            bf[t][s].u[3] = pack_bf16(r1.z, r1.w);
        }
    const int ntot = (E + 31) >> 5;
    for (int bt = wid; bt < ntot; bt += nw) {
        const int idx = (bt << 5) + c;
        const bool valid = idx < E;
        const int eid = valid ? idx : 0;
        const int se = src_idx[eid];
        const int d = dst_idx[eid];
        const float cjci = valid ? cj[se] * ci[d] : 0.0f;
        int pd = -1;
        float a0 = 0.0f, a1 = 0.0f;
        batch_body(eid, se, d, cjci, bf, pw4, sw4, ft4, weight, out,
                   h, c, pd, a0, a1);
        if (pd >= 0) {
            unsafeAtomicAdd(&out[(size_t)pd * 64 + c], a0);
            unsafeAtomicAdd(&out[(size_t)pd * 64 + 32 + c], a1);
        }
    }
}

extern "C" void kernel_launch(void* const* d_in, const int* in_sizes, int n_in,
                              void* d_out, int out_size, void* d_ws, size_t ws_size,
                              hipStream_t stream) {
    const float* weight    = (const float*)d_in[0];
    const float* prob_w    = (const float*)d_in[1];
    const float* rscore_w  = (const float*)d_in[2];
    const float* review_w  = (const float*)d_in[3];
    const float* feat      = (const float*)d_in[4];
    const float* cj        = (const float*)d_in[5];
    const float* ci        = (const float*)d_in[6];
    const int*   src_idx   = (const int*)d_in[7];
    const int*   dst_idx   = (const int*)d_in[8];
    float* out = (float*)d_out;
    const int E = in_sizes[7];
    const int N_DST = in_sizes[6];
    const int N_SRC = in_sizes[0] / 64;
    const int NB = (N_DST + BROWS - 1) >> BSHIFT;   // 1563 for N_DST=100000

    hipMemsetAsync(d_out, 0, (size_t)out_size * sizeof(float), stream);

    // ws: ghist[2048] | gcursor[2048] | gbase[2049] | pad->32KB |
    //     recs int2[E] | recsS int2[E] | weightB ushort[N_SRC*64]
    const size_t rec_off = 32768;
    const size_t wb_off = rec_off + 2 * (size_t)E * sizeof(int2);
    const size_t need = wb_off + (size_t)N_SRC * 64 * sizeof(unsigned short);
    if (ws_size < need || NB > MAXNB - 1 || N_SRC > (1 << 20) || E > (1 << 21)) {
        k_direct<<<2048, 256, 0, stream>>>(weight, prob_w, rscore_w, review_w, feat,
                                           cj, ci, src_idx, dst_idx, out, E);
        return;
    }
    int* ghist   = (int*)d_ws;
    int* gcursor = ghist + 2048;
    int* gbase   = ghist + 4096;
    int2* recs   = (int2*)((char*)d_ws + rec_off);
    int2* recsS  = recs + E;
    unsigned short* weightB = (unsigned short*)((char*)d_ws + wb_off);

    hipMemsetAsync(ghist, 0, 2048 * sizeof(int), stream);

    const int nchunk = (E + CHUNK - 1) / CHUNK;
    k_wconv<<<1024, 256, 0, stream>>>(weight, weightB, N_SRC * 64);
    k_hist<<<nchunk, 256, 0, stream>>>(dst_idx, ghist, E, NB);
    k_scan<<<1, 512, 0, stream>>>(ghist, gcursor, gbase, NB, E);
    k_scatter<<<nchunk, 256, 0, stream>>>(src_idx, dst_idx, gcursor, recs, E, NB);
    k_sortbucket<<<NB, 256, 0, stream>>>(recs, gbase, recsS);
    k_main<<<2048, 256, 0, stream>>>(weightB, prob_w, rscore_w, review_w, feat,
                                     cj, ci, recsS, out, E);
}